// Round 2
// baseline (133.902 us; speedup 1.0000x reference)
//
#include <hip/hip_runtime.h>
#include <math.h>

// Tiles: B*NTH*NTW = 64*56*56
constexpr int TT = 64 * 56 * 56;   // 200704 == 6272 * 32
// M = 8 slots, DF = 8 flux dims, output row = 11 floats; tile = 88 floats.
//
// 8 LANES per tile: lane L of a wave = (tile L>>3, row L&7). 25088 waves,
// coalesced float2/float4 loads ALL hoisted to kernel entry (no divergent
// dependent gather: the matched true-row record is routed to its destination
// lane via 10 sub-group shuffles of the pre-loaded own-row registers).
// Per-wave LDS region -> no __syncthreads needed: intra-wave lgkmcnt(0)
// suffices for cross-lane LDS visibility. Output stored nontemporal
// (write-once, never re-read) via native ext_vector float4 (the builtin
// rejects HIP's float4 class type).
typedef float fx4 __attribute__((ext_vector_type(4)));

__global__ __launch_bounds__(256) void mvd_coop(
    const float2* __restrict__ el2,   // est_locs  [TT*8] float2 rows
    const float2* __restrict__ tl2,   // true_locs [TT*8] float2 rows
    const float4* __restrict__ tf4,   // true_fluxes [TT*16] float4
    const int*    __restrict__ en_,
    const int*    __restrict__ tn_,
    float4*       __restrict__ out4)  // [TT*22]
{
#pragma clang fp contract(off)
    const int w    = threadIdx.x >> 6;      // wave in block (0..3)
    const int L    = threadIdx.x & 63;      // lane
    const int tloc = L >> 3;                // tile within wave (0..7)
    const int r    = L & 7;                 // row within tile
    const int tb   = blockIdx.x * 32 + w * 8;   // wave's first tile
    const int gt   = tb + tloc;             // this lane's tile
    const int g    = gt * 8 + r;            // this lane's global row

    __shared__ float s_buf[4][704];         // 8 tiles * 88 floats per wave
    float* sw = s_buf[w];

    // ---- all global loads up front, fully coalesced, one latency to hide
    const int en = en_[gt];
    const int tn = tn_[gt];
    const float2 eL = el2[g];               // est loc, own row
    const float2 tL = tl2[g];               // true loc, own row (unmasked record)
    const float4 f0 = tf4[2 * g];           // true fluxes, own row
    const float4 f1 = tf4[2 * g + 1];

    // masked values exactly as numpy builds them (FAR=100 sentinel)
    const float ex = (r < en) ? eL.x : 100.0f;
    const float ey = (r < en) ? eL.y : 100.0f;
    const float tx = (r < tn) ? tL.x : 100.0f;
    const float ty = (r < tn) ? tL.y : 100.0f;

    // d[j] = dist(est row r, true col j). Same op order as numpy
    // (contract off) + IEEE sqrtf == np.sqrt bitwise (ties must match:
    // sqrt rounding can merge squared-distinct values).
    float d[8];
#pragma unroll
    for (int j = 0; j < 8; j++) {
        const float txj = __shfl(tx, j, 8);
        const float tyj = __shfl(ty, j, 8);
        const float dx = ex - txj;
        const float dy = ey - tyj;
        const float dx2 = dx * dx;
        const float dy2 = dy * dy;
        d[j] = sqrtf(dx2 + dy2);
    }

    // m2 (own est row): argmin_j, strict '<' ascending == numpy first-occ.
    float rmin = 1e30f; int m2o = 0;
#pragma unroll
    for (int j = 0; j < 8; j++)
        if (d[j] < rmin) { rmin = d[j]; m2o = j; }

    // m1[j] = argmin over rows (first occurrence): 3-step min butterfly
    // within the 8-lane group, then ballot + ffs picks the smallest row
    // holding the min (== numpy tie-break).
    const int gbase = L & 56;
    int m1p = 0;
#pragma unroll
    for (int j = 0; j < 8; j++) {
        float dm = d[j];
#pragma unroll
        for (int s = 1; s < 8; s <<= 1) {
            const float o = __shfl_xor(dm, s);
            dm = (o < dm) ? o : dm;
        }
        const unsigned long long bal = __ballot(d[j] == dm);
        const int b = (int)((bal >> gbase) & 0xFFull);   // nonzero
        m1p |= (__ffs(b) - 1) << (3 * j);
    }

    // one2one for k = r (own column position)
    const int m1r = (m1p >> (3 * r)) & 7;       // match1[r]
    const int m1j = (m1p >> (3 * m2o)) & 7;     // match1[match2[r]]
    const bool o2o = (m1j == r) && (m1r < en) && (m2o < tn);

    // scatter fold over k=0..7 ascending (last-wins == numpy fancy assign):
    // row m1[k] takes true row m2[k]
    const int contrib = o2o ? ((8 | m2o) << (4 * m1r)) : 0;
    const int cmask   = o2o ? (0xF      << (4 * m1r)) : 0;
    int wrd = 0;
#pragma unroll
    for (int s = 0; s < 8; s++) {
        const int cw = __shfl(contrib, s, 8);
        const int cm = __shfl(cmask,  s, 8);
        wrd = (wrd & ~cm) | cw;
    }

    // this lane's output row r: source true row j if matched
    const int  v = (wrd >> (4 * r)) & 15;
    const bool matched = (v & 8) != 0;
    const int  j = v & 7;

    // Route row j's record here via sub-group shuffles of the registers
    // every lane already holds (replaces the divergent dependent gather).
    const float sx = __shfl(tL.x, j, 8);
    const float sy = __shfl(tL.y, j, 8);
    const float s2 = __shfl(f0.x, j, 8);
    const float s3 = __shfl(f0.y, j, 8);
    const float s4 = __shfl(f0.z, j, 8);
    const float s5 = __shfl(f0.w, j, 8);
    const float s6 = __shfl(f1.x, j, 8);
    const float s7 = __shfl(f1.y, j, 8);
    const float s8 = __shfl(f1.z, j, 8);
    const float s9 = __shfl(f1.w, j, 8);

    const float o0  = matched ? sx : 0.0f;
    const float o1  = matched ? sy : 0.0f;
    const float o2  = matched ? s2 : 0.0f;
    const float o3  = matched ? s3 : 0.0f;
    const float o4  = matched ? s4 : 0.0f;
    const float o5  = matched ? s5 : 0.0f;
    const float o6  = matched ? s6 : 0.0f;
    const float o7  = matched ? s7 : 0.0f;
    const float o8  = matched ? s8 : 0.0f;
    const float o9  = matched ? s9 : 0.0f;
    const float o10 = matched ? 1.0f : 0.0f;  // o2o implies j < tn

    {
        float* row = sw + tloc * 88 + r * 11;
        row[0]=o0; row[1]=o1; row[2]=o2; row[3]=o3; row[4]=o4; row[5]=o5;
        row[6]=o6; row[7]=o7; row[8]=o8; row[9]=o9; row[10]=o10;
    }
    // Per-wave LDS region: intra-wave write->read needs only lgkmcnt(0),
    // not a block barrier (waves are fully decoupled).
    asm volatile("s_waitcnt lgkmcnt(0)" ::: "memory");

    // wave's LDS region is CONTIGUOUS and equals the output layout:
    // 8 tiles * 22 float4 = 176 float4 -> 3 coalesced dwordx4 stores.
    const fx4* sw4 = (const fx4*)sw;
    fx4* ob = (fx4*)(out4 + (size_t)tb * 22);
#pragma unroll
    for (int k = 0; k < 3; k++) {
        const int fidx = L + 64 * k;
        if (fidx < 176) __builtin_nontemporal_store(sw4[fidx], &ob[fidx]);
    }
}

extern "C" void kernel_launch(void* const* d_in, const int* in_sizes, int n_in,
                              void* d_out, int out_size, void* d_ws, size_t ws_size,
                              hipStream_t stream) {
    const float* est_locs    = (const float*)d_in[0];
    const float* true_locs   = (const float*)d_in[1];
    const float* true_fluxes = (const float*)d_in[2];
    const int*   est_n       = (const int*)d_in[3];
    const int*   true_n      = (const int*)d_in[4];
    float* out = (float*)d_out;

    mvd_coop<<<TT / 32, 256, 0, stream>>>(
        (const float2*)est_locs, (const float2*)true_locs,
        (const float4*)true_fluxes, est_n, true_n, (float4*)out);
}